// Round 2
// baseline (629.204 us; speedup 1.0000x reference)
//
#include <hip/hip_runtime.h>
#include <hip/hip_bf16.h>
#include <stdint.h>

#define GLOBAL_AS __attribute__((address_space(1)))
#define LDS_AS    __attribute__((address_space(3)))

typedef __attribute__((ext_vector_type(8))) short          short8;
typedef __attribute__((ext_vector_type(4))) float          floatx4;
typedef __attribute__((ext_vector_type(4))) unsigned short ushort4v;

static __device__ __forceinline__ unsigned short f2bf_bits(float f) {
    union { float f; unsigned int u; } v; v.f = f;
    unsigned int r = v.u + 0x7FFFu + ((v.u >> 16) & 1u);   // RNE
    return (unsigned short)(r >> 16);
}

static __device__ __forceinline__ floatx4 mfma16(short8 a, short8 b, floatx4 c) {
    return __builtin_amdgcn_mfma_f32_16x16x32_bf16(a, b, c, 0, 0, 0);
}

// ---------------------------------------------------------------------------
// Generic gemm_bt (kept for GEMM1 only): C[M,N] = A[M,K] * B^T, B row-major [N,K].
// EPI 0: +bias[row], bf16 store.
// ---------------------------------------------------------------------------
template<int BM, int BN, int BK, int WM, int WN, bool A_F32, bool B_F32, int EPI>
__global__ __launch_bounds__(256, 2)
void gemm_bt(const void* __restrict__ Ap, const void* __restrict__ Bp,
             const float* __restrict__ bias, void* __restrict__ Cp,
             int lda, int ldb, int ldc, int klen)
{
    constexpr int NWM = BM / WM;
    constexpr int NWN = BN / WN;
    static_assert(NWM * NWN == 4, "4 waves per block");
    constexpr int FM = WM / 16;
    constexpr int FN = WN / 16;

    __shared__ __align__(16) unsigned short As[BM * BK];
    __shared__ __align__(16) unsigned short Bs[BN * BK];

    const int tid  = threadIdx.x;
    const int lane = tid & 63;
    const int wave = tid >> 6;
    const int wm   = (wave % NWM) * WM;
    const int wn   = (wave / NWM) * WN;
    const int quad = lane >> 4;
    const int l16  = lane & 15;
    const long m0 = (long)blockIdx.x * BM;
    const long n0 = (long)blockIdx.y * BN;

    floatx4 acc[FM][FN];
#pragma unroll
    for (int i = 0; i < FM; ++i)
#pragma unroll
        for (int j = 0; j < FN; ++j) {
            floatx4 z = {0.f, 0.f, 0.f, 0.f};
            acc[i][j] = z;
        }

    for (int kk = 0; kk < klen; kk += BK) {
        {   // stage A
            constexpr int CH = BM * BK / 8;
            if constexpr (A_F32) {
                const float* A = (const float*)Ap;
#pragma unroll
                for (int c0 = 0; c0 < CH; c0 += 256) {
                    int c = c0 + tid, row = c / (BK / 8), col = (c % (BK / 8)) * 8;
                    const float* src = A + (m0 + row) * (long)lda + (kk + col);
                    floatx4 f0 = *(const floatx4*)(src);
                    floatx4 f1 = *(const floatx4*)(src + 4);
                    union { unsigned short u[8]; short8 v; } pk;
                    pk.u[0] = f2bf_bits(f0.x); pk.u[1] = f2bf_bits(f0.y);
                    pk.u[2] = f2bf_bits(f0.z); pk.u[3] = f2bf_bits(f0.w);
                    pk.u[4] = f2bf_bits(f1.x); pk.u[5] = f2bf_bits(f1.y);
                    pk.u[6] = f2bf_bits(f1.z); pk.u[7] = f2bf_bits(f1.w);
                    *(short8*)&As[c * 8] = pk.v;
                }
            } else {
                const unsigned short* A = (const unsigned short*)Ap;
#pragma unroll
                for (int c0 = 0; c0 < CH; c0 += 256) {
                    int c = c0 + tid, row = c / (BK / 8), col = (c % (BK / 8)) * 8;
                    const unsigned short* src = A + (m0 + row) * (long)lda + (kk + col);
                    __builtin_amdgcn_global_load_lds((const GLOBAL_AS unsigned int*)src,
                                                     (LDS_AS unsigned int*)&As[c * 8], 16, 0, 0);
                }
            }
        }
        {   // stage B
            constexpr int CH = BN * BK / 8;
            if constexpr (B_F32) {
                const float* B = (const float*)Bp;
#pragma unroll
                for (int c0 = 0; c0 < CH; c0 += 256) {
                    int c = c0 + tid, row = c / (BK / 8), col = (c % (BK / 8)) * 8;
                    const float* src = B + (n0 + row) * (long)ldb + (kk + col);
                    floatx4 f0 = *(const floatx4*)(src);
                    floatx4 f1 = *(const floatx4*)(src + 4);
                    union { unsigned short u[8]; short8 v; } pk;
                    pk.u[0] = f2bf_bits(f0.x); pk.u[1] = f2bf_bits(f0.y);
                    pk.u[2] = f2bf_bits(f0.z); pk.u[3] = f2bf_bits(f0.w);
                    pk.u[4] = f2bf_bits(f1.x); pk.u[5] = f2bf_bits(f1.y);
                    pk.u[6] = f2bf_bits(f1.z); pk.u[7] = f2bf_bits(f1.w);
                    *(short8*)&Bs[c * 8] = pk.v;
                }
            } else {
                const unsigned short* B = (const unsigned short*)Bp;
#pragma unroll
                for (int c0 = 0; c0 < CH; c0 += 256) {
                    int c = c0 + tid, row = c / (BK / 8), col = (c % (BK / 8)) * 8;
                    const unsigned short* src = B + (n0 + row) * (long)ldb + (kk + col);
                    __builtin_amdgcn_global_load_lds((const GLOBAL_AS unsigned int*)src,
                                                     (LDS_AS unsigned int*)&Bs[c * 8], 16, 0, 0);
                }
            }
        }
        __syncthreads();

#pragma unroll
        for (int ks = 0; ks < BK; ks += 32) {
            short8 af[FM], bfr[FN];
#pragma unroll
            for (int i = 0; i < FM; ++i)
                af[i] = *(const short8*)&As[(wm + i * 16 + l16) * BK + ks + quad * 8];
#pragma unroll
            for (int j = 0; j < FN; ++j)
                bfr[j] = *(const short8*)&Bs[(wn + j * 16 + l16) * BK + ks + quad * 8];
#pragma unroll
            for (int i = 0; i < FM; ++i)
#pragma unroll
                for (int j = 0; j < FN; ++j)
                    acc[i][j] = mfma16(af[i], bfr[j], acc[i][j]);
        }
        __syncthreads();
    }

#pragma unroll
    for (int i = 0; i < FM; ++i)
#pragma unroll
        for (int j = 0; j < FN; ++j)
#pragma unroll
            for (int v = 0; v < 4; ++v) {
                long r = m0 + wm + i * 16 + quad * 4 + v;
                long c = n0 + wn + j * 16 + l16;
                float val = acc[i][j][v] + bias[r];
                ((unsigned short*)Cp)[r * (long)ldc + c] = f2bf_bits(val);
            }
}

// ---------------------------------------------------------------------------
// agg_kernel: parts[z] = adj[m0:m0+64, z*2048:(z+1)*2048] * supT^T
// BM=64, BN=256(full), BK=64, split-K=4. Waves 2x2 (WM=32, WN=128), FM=2 FN=8.
// adj (fp32) register-prefetched one iteration ahead; supT via global_load_lds.
// ---------------------------------------------------------------------------
__global__ __launch_bounds__(256, 2)
void agg_kernel(const float* __restrict__ adj, const unsigned short* __restrict__ supT,
                float* __restrict__ parts)
{
    constexpr int BK = 64, KLEN = 2048;
    constexpr long PST = 8192L * 256L;

    __shared__ __align__(16) unsigned short As[64 * BK];
    __shared__ __align__(16) unsigned short Bs[256 * BK];

    const int tid  = threadIdx.x;
    const int lane = tid & 63;
    const int wave = tid >> 6;
    const int wm   = (wave & 1) * 32;
    const int wn   = (wave >> 1) * 128;
    const int quad = lane >> 4;
    const int l16  = lane & 15;
    const long m0 = (long)blockIdx.x * 64;
    const long k0 = (long)blockIdx.z * (long)KLEN;

    // A staging: 2 chunks/thread (c = tid, tid+256); row = c/8, col = (c&7)*8
    const int ar = tid >> 3;
    const int ac = (tid & 7) * 8;
    const float* aptr0 = adj + (m0 + ar) * 8192L + k0 + ac;
    const float* aptr1 = aptr0 + 32 * 8192L;

    floatx4 acc[2][8];
#pragma unroll
    for (int i = 0; i < 2; ++i)
#pragma unroll
        for (int j = 0; j < 8; ++j) {
            floatx4 z = {0.f, 0.f, 0.f, 0.f};
            acc[i][j] = z;
        }

    // prefetch iteration 0
    floatx4 a0 = *(const floatx4*)(aptr0);
    floatx4 a1 = *(const floatx4*)(aptr0 + 4);
    floatx4 a2 = *(const floatx4*)(aptr1);
    floatx4 a3 = *(const floatx4*)(aptr1 + 4);

    for (int kk = 0; kk < KLEN; kk += BK) {
        // issue B global->LDS (supT panel rows 0..255, k slice)
#pragma unroll
        for (int c0 = 0; c0 < 2048; c0 += 256) {
            int c = c0 + tid, row = c >> 3, col = (c & 7) * 8;
            const unsigned short* src = supT + row * 8192L + (k0 + kk + col);
            __builtin_amdgcn_global_load_lds((const GLOBAL_AS unsigned int*)src,
                                             (LDS_AS unsigned int*)&Bs[c * 8], 16, 0, 0);
        }
        // convert + write prefetched A regs to LDS
        {
            union { unsigned short u[8]; short8 v; } p0, p1;
            p0.u[0] = f2bf_bits(a0.x); p0.u[1] = f2bf_bits(a0.y);
            p0.u[2] = f2bf_bits(a0.z); p0.u[3] = f2bf_bits(a0.w);
            p0.u[4] = f2bf_bits(a1.x); p0.u[5] = f2bf_bits(a1.y);
            p0.u[6] = f2bf_bits(a1.z); p0.u[7] = f2bf_bits(a1.w);
            p1.u[0] = f2bf_bits(a2.x); p1.u[1] = f2bf_bits(a2.y);
            p1.u[2] = f2bf_bits(a2.z); p1.u[3] = f2bf_bits(a2.w);
            p1.u[4] = f2bf_bits(a3.x); p1.u[5] = f2bf_bits(a3.y);
            p1.u[6] = f2bf_bits(a3.z); p1.u[7] = f2bf_bits(a3.w);
            *(short8*)&As[tid * 8] = p0.v;
            *(short8*)&As[(tid + 256) * 8] = p1.v;
        }
        __syncthreads();

        // prefetch next iteration's A (overlaps MFMA below)
        if (kk + BK < KLEN) {
            aptr0 += BK; aptr1 += BK;
            a0 = *(const floatx4*)(aptr0);
            a1 = *(const floatx4*)(aptr0 + 4);
            a2 = *(const floatx4*)(aptr1);
            a3 = *(const floatx4*)(aptr1 + 4);
        }

#pragma unroll
        for (int ks = 0; ks < BK; ks += 32) {
            short8 af[2], bfr[8];
#pragma unroll
            for (int i = 0; i < 2; ++i)
                af[i] = *(const short8*)&As[(wm + i * 16 + l16) * BK + ks + quad * 8];
#pragma unroll
            for (int j = 0; j < 8; ++j)
                bfr[j] = *(const short8*)&Bs[(wn + j * 16 + l16) * BK + ks + quad * 8];
#pragma unroll
            for (int i = 0; i < 2; ++i)
#pragma unroll
                for (int j = 0; j < 8; ++j)
                    acc[i][j] = mfma16(af[i], bfr[j], acc[i][j]);
        }
        __syncthreads();
    }

    float* dst = parts + (long)blockIdx.z * PST;
#pragma unroll
    for (int i = 0; i < 2; ++i)
#pragma unroll
        for (int j = 0; j < 8; ++j)
#pragma unroll
            for (int v = 0; v < 4; ++v) {
                long r = m0 + wm + i * 16 + quad * 4 + v;
                long c = wn + j * 16 + l16;
                dst[r * 256L + c] = acc[i][j][v];
            }
}

// ---------------------------------------------------------------------------
// hht_kernel: out = h * h^T, h bf16 [8192,256]. 128x128 tile, no LDS (K=256,
// fragments straight from global/L2). Symmetric output => store each tile
// transposed with contiguous float4 per lane.
// ---------------------------------------------------------------------------
__global__ __launch_bounds__(256, 2)
void hht_kernel(const unsigned short* __restrict__ h, float* __restrict__ out)
{
    const int tid  = threadIdx.x;
    const int lane = tid & 63;
    const int wave = tid >> 6;
    const int wm   = (wave & 1) * 64;
    const int wn   = (wave >> 1) * 64;
    const int quad = lane >> 4;
    const int l16  = lane & 15;
    const long m0 = (long)blockIdx.x * 128;
    const long n0 = (long)blockIdx.y * 128;

    floatx4 acc[4][4];
#pragma unroll
    for (int i = 0; i < 4; ++i)
#pragma unroll
        for (int j = 0; j < 4; ++j) {
            floatx4 z = {0.f, 0.f, 0.f, 0.f};
            acc[i][j] = z;
        }

    const unsigned short* arow = h + (m0 + wm + l16) * 256L + quad * 8;
    const unsigned short* brow = h + (n0 + wn + l16) * 256L + quad * 8;

#pragma unroll
    for (int ks = 0; ks < 256; ks += 32) {
        short8 af[4], bfr[4];
#pragma unroll
        for (int i = 0; i < 4; ++i)
            af[i] = *(const short8*)(arow + i * 16 * 256L + ks);
#pragma unroll
        for (int j = 0; j < 4; ++j)
            bfr[j] = *(const short8*)(brow + j * 16 * 256L + ks);
#pragma unroll
        for (int i = 0; i < 4; ++i)
#pragma unroll
            for (int j = 0; j < 4; ++j)
                acc[i][j] = mfma16(af[i], bfr[j], acc[i][j]);
    }

    // C symmetric: value(i,j,lane) = out[r][c] = out[c][r]; lane's 4 vals are
    // 4 consecutive cols of row c  => one float4 store per fragment.
#pragma unroll
    for (int i = 0; i < 4; ++i)
#pragma unroll
        for (int j = 0; j < 4; ++j) {
            long rt = n0 + wn + j * 16 + l16;
            long ct = m0 + wm + i * 16 + quad * 4;
            *(floatx4*)&out[rt * 8192L + ct] = acc[i][j];
        }
}

// Wt[n][k] = bf16(W[k][n])
__global__ void transpose_w_kernel(const float* __restrict__ W, unsigned short* __restrict__ Wt)
{
    int idx = blockIdx.x * 256 + threadIdx.x;
    int n = idx >> 8;
    int k = idx & 255;
    Wt[n * 256 + k] = f2bf_bits(W[k * 256 + n]);
}

// h = bf16(relu(p0+p1+p2+p3))
__global__ void reduce_relu_kernel(const float* __restrict__ p, unsigned short* __restrict__ h)
{
    constexpr long PST = 8192L * 256L;
    int i = (blockIdx.x * 256 + threadIdx.x) * 4;
    floatx4 a = *(const floatx4*)(p + i);
    floatx4 b = *(const floatx4*)(p + PST + i);
    floatx4 c = *(const floatx4*)(p + 2 * PST + i);
    floatx4 d = *(const floatx4*)(p + 3 * PST + i);
    ushort4v o;
    o.x = f2bf_bits(fmaxf(a.x + b.x + c.x + d.x, 0.f));
    o.y = f2bf_bits(fmaxf(a.y + b.y + c.y + d.y, 0.f));
    o.z = f2bf_bits(fmaxf(a.z + b.z + c.z + d.z, 0.f));
    o.w = f2bf_bits(fmaxf(a.w + b.w + c.w + d.w, 0.f));
    *(ushort4v*)&h[i] = o;
}

extern "C" void kernel_launch(void* const* d_in, const int* in_sizes, int n_in,
                              void* d_out, int out_size, void* d_ws, size_t ws_size,
                              hipStream_t stream)
{
    const float* x   = (const float*)d_in[0];   // [8192,256]
    const float* adj = (const float*)d_in[1];   // [8192,8192]
    const float* W   = (const float*)d_in[2];   // [256,256]
    const float* b   = (const float*)d_in[3];   // [256]
    float* out = (float*)d_out;                 // [8192,8192]

    char* ws = (char*)d_ws;
    // ws: Wt 128KB | supT 4MB | h 4MB | parts 32MB  (~40.2 MB)
    unsigned short* Wt    = (unsigned short*)(ws);
    unsigned short* supT  = (unsigned short*)(ws + 131072);
    unsigned short* h     = (unsigned short*)(ws + 4325376);
    float*          parts = (float*)         (ws + 8519680);

    // 1) Wt = transpose(bf16(W))
    transpose_w_kernel<<<256, 256, 0, stream>>>(W, Wt);

    // 2) supT[256,8192] = Wt * x^T + b[row]
    gemm_bt<32, 256, 64, 32, 64, false, true, 0>
        <<<dim3(8, 32, 1), 256, 0, stream>>>(Wt, x, b, supT, 256, 256, 8192, 256);

    // 3) parts[z] = adj_z * supT^T   (split-K=4)
    agg_kernel<<<dim3(128, 1, 4), 256, 0, stream>>>(adj, supT, parts);

    // 4) h = bf16(relu(sum parts))
    reduce_relu_kernel<<<2048, 256, 0, stream>>>(parts, h);

    // 5) out = h * h^T
    hht_kernel<<<dim3(64, 64, 1), 256, 0, stream>>>(h, out);
}